// Round 7
// baseline (226.022 us; speedup 1.0000x reference)
//
#include <hip/hip_runtime.h>
#include <hip/hip_bf16.h>
#include <math.h>

#define N_TOK 2048
#define C_DIM 512
#define H_NUM 8
#define DH 64
#define M_LM 64
#define SEG 32
#define KL 4
#define SCALE 0.125f

typedef __attribute__((ext_vector_type(8))) short short8;
typedef __attribute__((ext_vector_type(4))) float f32x4;

__device__ inline unsigned short f2bf(float f) {
  unsigned u = __float_as_uint(f);
  u += 0x7FFF + ((u >> 16) & 1);
  return (unsigned short)(u >> 16);
}
__device__ inline float bf2f(unsigned short h) {
  return __uint_as_float(((unsigned)h) << 16);
}

// ---------------------------------------------------------------------------
// Q/K fp32 GEMM — byte-identical to R5/R6 (bit-identical chain to R0;
// route path frozen). Do not touch.
// ---------------------------------------------------------------------------
__global__ __launch_bounds__(256) void gemm_qk(
    const float* __restrict__ A, const float* __restrict__ B,
    float* __restrict__ out_q, float* __restrict__ out_k)
{
  __shared__ float As[32][68];
  __shared__ float Bs[32][68];
  int tid = threadIdx.x;
  int tx = tid & 15, ty = tid >> 4;
  int row0 = blockIdx.y << 6;
  int col0 = blockIdx.x << 6;
  float acc[4][4] = {};
  int kk = tid & 31, rr = tid >> 5;

  float pa[8], pb[8];
#pragma unroll
  for (int i = 0; i < 8; i++) {
    pa[i] = A[(size_t)(row0 + rr + i * 8) * 512 + kk];
    pb[i] = B[(size_t)(col0 + rr + i * 8) * 512 + kk];
  }

  for (int k0 = 0; k0 < 512; k0 += 32) {
    __syncthreads();
#pragma unroll
    for (int i = 0; i < 8; i++) {
      As[kk][rr + i * 8] = pa[i];
      Bs[kk][rr + i * 8] = pb[i];
    }
    __syncthreads();
    if (k0 + 32 < 512) {
#pragma unroll
      for (int i = 0; i < 8; i++) {
        pa[i] = A[(size_t)(row0 + rr + i * 8) * 512 + k0 + 32 + kk];
        pb[i] = B[(size_t)(col0 + rr + i * 8) * 512 + k0 + 32 + kk];
      }
    }
#pragma unroll
    for (int kk2 = 0; kk2 < 32; kk2++) {
      float a[4], b[4];
      *(float4*)a = *(const float4*)&As[kk2][ty << 2];
      *(float4*)b = *(const float4*)&Bs[kk2][tx << 2];
#pragma unroll
      for (int i = 0; i < 4; i++)
#pragma unroll
        for (int j = 0; j < 4; j++) acc[i][j] += a[i] * b[j];
    }
  }

  int t = col0 >> 9;
  int h = (col0 >> 6) & 7;
  float* dst = (t == 0) ? out_q : out_k;
#pragma unroll
  for (int i = 0; i < 4; i++) {
    int n = row0 + (ty << 2) + i;
#pragma unroll
    for (int j = 0; j < 4; j++) {
      int d = (tx << 2) + j;
      dst[(size_t)((h << 11) + n) * DH + d] = acc[i][j];
    }
  }
}

// ---------------------------------------------------------------------------
// Fused 2-term bf16 splits (byte-identical to R5/R6).
// ---------------------------------------------------------------------------
__global__ void split3_kernel(const float* __restrict__ x, const float* __restrict__ wv,
                              const float* __restrict__ wp,
                              unsigned short* __restrict__ X2,
                              unsigned short* __restrict__ W2v,
                              unsigned short* __restrict__ WP2)
{
  int idx = blockIdx.x * 256 + threadIdx.x;
  const float* src; unsigned short* dst; int li;
  if (idx < 1048576)      { src = x;  dst = X2;  li = idx; }
  else if (idx < 1310720) { src = wv; dst = W2v; li = idx - 1048576; }
  else                    { src = wp; dst = WP2; li = idx - 1310720; }
  int r = li >> 9, k = li & 511;
  float a = src[li];
  unsigned short h1 = f2bf(a);
  float r1 = a - bf2f(h1);
  dst[(size_t)(r << 10) + k] = h1;
  dst[(size_t)(r << 10) + 512 + k] = f2bf(r1);
}

// ---------------------------------------------------------------------------
// bf16-split MFMA GEMM (byte-identical to R5/R6).
// ---------------------------------------------------------------------------
__global__ __launch_bounds__(256) void gemm_mfma(
    const unsigned short* __restrict__ A2, const unsigned short* __restrict__ B2,
    float* __restrict__ ov, float* __restrict__ ofull,
    const float* __restrict__ bias, int ldout, int mode)
{
  __shared__ short Al[4096];
  __shared__ short Bl[4096];
  int tid = threadIdx.x;
  int lane = tid & 63, w = tid >> 6;
  int row0 = blockIdx.y << 6, col0 = blockIdx.x << 6;
  int wr = (w >> 1) * 32, wc = (w & 1) * 32;
  int m_lo = tid & 7, h8 = (tid >> 3) & 7, m_hi = tid >> 6;
  int ms = m_hi * 8 + m_lo;
  int q = lane >> 4, ln = lane & 15;

  f32x4 acc[2][2];
#pragma unroll
  for (int mi = 0; mi < 2; mi++)
#pragma unroll
    for (int ni = 0; ni < 2; ni++)
#pragma unroll
      for (int r = 0; r < 4; r++) acc[mi][ni][r] = 0.0f;

  for (int s = 0; s < 24; s++) {
    int ka = (s < 8) ? s * 64 : (s < 16) ? 512 + (s - 8) * 64 : (s - 16) * 64;
    int kb = (s < 8) ? s * 64 : (s < 16) ? (s - 8) * 64 : 512 + (s - 16) * 64;
    short8 a0 = *(const short8*)(A2 + (size_t)(row0 + ms) * 1024 + ka + h8 * 8);
    short8 a1 = *(const short8*)(A2 + (size_t)(row0 + ms + 32) * 1024 + ka + h8 * 8);
    short8 b0 = *(const short8*)(B2 + (size_t)(col0 + ms) * 1024 + kb + h8 * 8);
    short8 b1 = *(const short8*)(B2 + (size_t)(col0 + ms + 32) * 1024 + kb + h8 * 8);
    __syncthreads();
    *(short8*)&Al[(h8 * 64 + ms) * 8] = a0;
    *(short8*)&Al[(h8 * 64 + ms + 32) * 8] = a1;
    *(short8*)&Bl[(h8 * 64 + ms) * 8] = b0;
    *(short8*)&Bl[(h8 * 64 + ms + 32) * 8] = b1;
    __syncthreads();
    short8 af[2][2], bf[2][2];
#pragma unroll
    for (int sub = 0; sub < 2; sub++)
#pragma unroll
      for (int i = 0; i < 2; i++) {
        af[sub][i] = *(const short8*)&Al[((sub * 4 + q) * 64 + wr + i * 16 + ln) * 8];
        bf[sub][i] = *(const short8*)&Bl[((sub * 4 + q) * 64 + wc + i * 16 + ln) * 8];
      }
#pragma unroll
    for (int sub = 0; sub < 2; sub++)
#pragma unroll
      for (int mi = 0; mi < 2; mi++)
#pragma unroll
        for (int ni = 0; ni < 2; ni++)
          acc[mi][ni] = __builtin_amdgcn_mfma_f32_16x16x32_bf16(
              af[sub][mi], bf[sub][ni], acc[mi][ni], 0, 0, 0);
  }

  if (mode == 0) {
    int hh = (col0 >> 6) & 7;
#pragma unroll
    for (int mi = 0; mi < 2; mi++)
#pragma unroll
      for (int ni = 0; ni < 2; ni++)
#pragma unroll
        for (int r = 0; r < 4; r++) {
          int row = row0 + wr + mi * 16 + q * 4 + r;
          int d = wc + ni * 16 + ln;
          ov[(size_t)((hh << 11) + row) * DH + d] = acc[mi][ni][r];
        }
  } else {
#pragma unroll
    for (int mi = 0; mi < 2; mi++)
#pragma unroll
      for (int ni = 0; ni < 2; ni++)
#pragma unroll
        for (int r = 0; r < 4; r++) {
          int row = row0 + wr + mi * 16 + q * 4 + r;
          int col = col0 + wc + ni * 16 + ln;
          ofull[(size_t)row * ldout + col] = acc[mi][ni][r] + bias[col];
        }
  }
}

// ---------------------------------------------------------------------------
// Centroids (byte-identical to R0).
// ---------------------------------------------------------------------------
__global__ void centroid_kernel(const float* __restrict__ kb, float* __restrict__ cent)
{
  int idx = blockIdx.x * blockDim.x + threadIdx.x;
  int m = (idx >> 6) & 63;
  int h = idx >> 12;
  int d = idx & 63;
  const float* base = kb + ((size_t)(h << 11) + m * SEG) * DH + d;
  float s = 0.f;
#pragma unroll
  for (int ss = 0; ss < SEG; ss++) s += base[(size_t)ss * DH];
  cent[idx] = s * (1.0f / SEG);
}

// ---------------------------------------------------------------------------
// Route + top-4 (byte-identical to R4-R6 passing version).
// ---------------------------------------------------------------------------
__global__ __launch_bounds__(256) void route_topk_kernel(
    const float* __restrict__ qb, const float* __restrict__ cent, int* __restrict__ topk)
{
  __shared__ float centT[64][65];
  __shared__ float qs[4][64];
  int tid = threadIdx.x;
  int wave = tid >> 6, lane = tid & 63;
  int qi = (blockIdx.x << 2) + wave;
  int h = qi >> 11;
  qs[wave][lane] = qb[(size_t)qi * DH + lane];
  const float4* c4 = (const float4*)(cent + ((size_t)h << 12));
#pragma unroll
  for (int i = 0; i < 4; i++) {
    int f4 = tid + 256 * i;
    int m = f4 >> 4;
    int d0 = (f4 & 15) * 4;
    float4 v = c4[f4];
    centT[d0][m] = v.x; centT[d0 + 1][m] = v.y;
    centT[d0 + 2][m] = v.z; centT[d0 + 3][m] = v.w;
  }
  __syncthreads();
  float dot = 0.f;
#pragma unroll
  for (int d = 0; d < 64; d++) dot += qs[wave][d] * centT[d][lane];
  float val = dot * SCALE;
  for (int r = 0; r < KL; r++) {
    float v = val;
    int id = lane;
#pragma unroll
    for (int off = 32; off; off >>= 1) {
      float ov = __shfl_xor(v, off, 64);
      int oi = __shfl_xor(id, off, 64);
      if (ov > v || (ov == v && oi < id)) { v = ov; id = oi; }
    }
    if (lane == 0) topk[qi * KL + r] = id;
    if (lane == id) val = -INFINITY;
  }
}

// ---------------------------------------------------------------------------
// Bin: bucket (query, slot) pairs by (h, seg). Entry = n | (r<<11), 13 bits.
// Order within a bucket is nondeterministic but partials are (q,r)-indexed,
// so the final output is deterministic.
// ---------------------------------------------------------------------------
__global__ void bin_kernel(const int* __restrict__ topk, int* __restrict__ cnt,
                           unsigned short* __restrict__ bucket)
{
  int qi = blockIdx.x * 256 + threadIdx.x;   // 0..16383
  int4 tk = *(const int4*)(topk + qi * KL);
  int segs[4] = {tk.x, tk.y, tk.z, tk.w};
  int h = qi >> 11, n = qi & 2047;
#pragma unroll
  for (int r = 0; r < KL; r++) {
    int hs = (h << 6) | segs[r];
    int pos = atomicAdd(&cnt[hs], 1);
    bucket[hs * 2048 + pos] = (unsigned short)(n | (r << 11));
  }
}

// ---------------------------------------------------------------------------
// Attend (segment-major): 4 blocks per (h,seg); K/V segment staged in LDS
// once; each wave processes 2 routed queries per iteration (16 streams of
// stride 32 over the bucket). Emits per-(q,r) softmax partials m,l and
// partial PV o[64].
// ---------------------------------------------------------------------------
__global__ __launch_bounds__(256) void attend_kernel(
    const float* __restrict__ qb, const float* __restrict__ kb,
    const float* __restrict__ vb, const int* __restrict__ cnt,
    const unsigned short* __restrict__ bucket,
    float2* __restrict__ pml, float* __restrict__ po)
{
  __shared__ float Kl[32 * 68];
  __shared__ float Vl[32 * 68];
  __shared__ float qs[4][2][64];
  __shared__ float ps[4][2][32];
  int b = blockIdx.x;              // 2048
  int hs = b >> 2, qt = b & 3;
  int h = hs >> 6, seg = hs & 63;
  int tid = threadIdx.x, w = tid >> 6, lane = tid & 63;
  {
    int row = tid >> 3, d0 = (tid & 7) * 8;
    const float* kr = kb + ((size_t)(h << 11) + seg * SEG + row) * DH + d0;
    const float* vr = vb + ((size_t)(h << 11) + seg * SEG + row) * DH + d0;
    *(float4*)&Kl[row * 68 + d0]     = *(const float4*)kr;
    *(float4*)&Kl[row * 68 + d0 + 4] = *(const float4*)(kr + 4);
    *(float4*)&Vl[row * 68 + d0]     = *(const float4*)vr;
    *(float4*)&Vl[row * 68 + d0 + 4] = *(const float4*)(vr + 4);
  }
  __syncthreads();
  int c = cnt[hs];
  int k2 = lane >> 1, half = lane & 1;
  int sid = (qt << 2) | w;         // 0..15
  for (int i0 = sid * 2; i0 < c; i0 += 32) {
    int i1 = i0 + 1;
    bool has2 = (i1 < c);          // wave-uniform
    int e0 = bucket[hs * 2048 + i0];
    int e1 = has2 ? bucket[hs * 2048 + i1] : e0;
    int n0 = e0 & 2047, r0 = (e0 >> 11) & 3;
    int n1 = e1 & 2047, r1 = (e1 >> 11) & 3;
    qs[w][0][lane] = qb[((size_t)(h << 11) + n0) * DH + lane];
    qs[w][1][lane] = qb[((size_t)(h << 11) + n1) * DH + lane];
    // scores: lane (k2, half) does half the dims of key k2, for both queries
    float a0 = 0.f, a1 = 0.f;
#pragma unroll
    for (int j = 0; j < 8; j++) {
      float4 kv = *(const float4*)&Kl[k2 * 68 + half * 32 + 4 * j];
      float4 q0 = *(const float4*)&qs[w][0][half * 32 + 4 * j];
      float4 q1 = *(const float4*)&qs[w][1][half * 32 + 4 * j];
      a0 += q0.x * kv.x + q0.y * kv.y + q0.z * kv.z + q0.w * kv.w;
      a1 += q1.x * kv.x + q1.y * kv.y + q1.z * kv.z + q1.w * kv.w;
    }
    a0 += __shfl_xor(a0, 1, 64);
    a1 += __shfl_xor(a1, 1, 64);
    float s0 = a0 * SCALE, s1 = a1 * SCALE;
    float m0 = s0, m1 = s1;
#pragma unroll
    for (int off = 2; off < 64; off <<= 1) {
      m0 = fmaxf(m0, __shfl_xor(m0, off, 64));
      m1 = fmaxf(m1, __shfl_xor(m1, off, 64));
    }
    float ex0 = expf(s0 - m0), ex1 = expf(s1 - m1);
    float l0 = ex0, l1 = ex1;
#pragma unroll
    for (int off = 2; off < 64; off <<= 1) {
      l0 += __shfl_xor(l0, off, 64);
      l1 += __shfl_xor(l1, off, 64);
    }
    if (half == 0) { ps[w][0][k2] = ex0; ps[w][1][k2] = ex1; }
    // partial PV: lane = d
    float o0 = 0.f, o1 = 0.f;
#pragma unroll
    for (int k = 0; k < 32; k++) {
      float vv = Vl[k * 68 + lane];
      o0 += ps[w][0][k] * vv;
      o1 += ps[w][1][k] * vv;
    }
    int p0 = (((h << 11) | n0) << 2) | r0;
    po[(size_t)p0 * 64 + lane] = o0;
    if (lane == 0) pml[p0] = make_float2(m0, l0);
    if (has2) {
      int p1 = (((h << 11) | n1) << 2) | r1;
      po[(size_t)p1 * 64 + lane] = o1;
      if (lane == 0) pml[p1] = make_float2(m1, l1);
    }
  }
}

// ---------------------------------------------------------------------------
// Combine the 4 per-segment partials per query; emit bf16 hi|lo split.
// ---------------------------------------------------------------------------
__global__ void combine_kernel(const float2* __restrict__ pml,
                               const float* __restrict__ po,
                               unsigned short* __restrict__ ao2)
{
  int idx = blockIdx.x * 256 + threadIdx.x;   // 0 .. 16384*64-1
  int d = idx & 63;
  int qi = idx >> 6;
  int h = qi >> 11, n = qi & 2047;
  float2 ml0 = pml[qi * 4 + 0], ml1 = pml[qi * 4 + 1];
  float2 ml2 = pml[qi * 4 + 2], ml3 = pml[qi * 4 + 3];
  float M = fmaxf(fmaxf(ml0.x, ml1.x), fmaxf(ml2.x, ml3.x));
  float w0 = expf(ml0.x - M), w1 = expf(ml1.x - M);
  float w2 = expf(ml2.x - M), w3 = expf(ml3.x - M);
  float L = w0 * ml0.y + w1 * ml1.y + w2 * ml2.y + w3 * ml3.y;
  float o = w0 * po[(size_t)(qi * 4 + 0) * 64 + d]
          + w1 * po[(size_t)(qi * 4 + 1) * 64 + d]
          + w2 * po[(size_t)(qi * 4 + 2) * 64 + d]
          + w3 * po[(size_t)(qi * 4 + 3) * 64 + d];
  o /= L;
  unsigned short hb = f2bf(o);
  unsigned short lb = f2bf(o - bf2f(hb));
  size_t off0 = (size_t)n * 1024 + (h << 6) + d;
  ao2[off0] = hb;
  ao2[off0 + 512] = lb;
}

// ---------------------------------------------------------------------------
extern "C" void kernel_launch(void* const* d_in, const int* in_sizes, int n_in,
                              void* d_out, int out_size, void* d_ws, size_t ws_size,
                              hipStream_t stream)
{
  const float* x      = (const float*)d_in[0];
  const float* w_qkv  = (const float*)d_in[1];
  const float* w_proj = (const float*)d_in[2];
  const float* b_proj = (const float*)d_in[3];
  float* out = (float*)d_out;

  float* base = (float*)d_ws;
  float* qbuf = base;                                   // 1,048,576 f
  float* kbuf = base + 1048576;
  float* vbuf = base + 2097152;
  float* cent = base + 3145728;                         // 32,768 f
  int*   topk = (int*)(base + 3178496);                 // 65,536 i
  unsigned short* X2  = (unsigned short*)(base + 3244032);  // 2048x1024 bf16
  unsigned short* W2v = (unsigned short*)(base + 4292608);  // 512x1024
  unsigned short* WP2 = (unsigned short*)(base + 4554752);  // 512x1024
  unsigned short* AO2 = X2;  // overlay: X2 dead after V GEMM
  int* cnt = (int*)(base + 4816896);                        // 512 ints
  unsigned short* bucket = (unsigned short*)(base + 4817408);  // 512*2048 u16
  float2* pml = (float2*)(base + 5341696);                  // 65,536 float2
  float* po   = base + 5472768;                             // 65,536*64 f

  // 1. fused 2-term bf16 splits
  split3_kernel<<<6144, 256, 0, stream>>>(x, w_qkv + 1024 * 512, w_proj,
                                          X2, W2v, WP2);
  // 2. Q/K fp32 (bit-identical chain to R0; route path frozen)
  {
    dim3 grid(1024 / 64, N_TOK / 64);
    gemm_qk<<<grid, 256, 0, stream>>>(x, w_qkv, qbuf, kbuf);
  }
  // 3. V via bf16-split MFMA
  {
    dim3 grid(512 / 64, N_TOK / 64);
    gemm_mfma<<<grid, 256, 0, stream>>>(X2, W2v, vbuf, nullptr, nullptr, 0, 0);
  }
  // 4. centroids
  centroid_kernel<<<(H_NUM * M_LM * DH) / 256, 256, 0, stream>>>(kbuf, cent);
  // 5. route + top-4 (bit-exact vs R0)
  route_topk_kernel<<<(H_NUM * N_TOK) / 4, 256, 0, stream>>>(qbuf, cent, topk);
  // 6. segment-major sparse attention
  hipMemsetAsync(cnt, 0, 512 * sizeof(int), stream);
  bin_kernel<<<64, 256, 0, stream>>>(topk, cnt, bucket);
  attend_kernel<<<2048, 256, 0, stream>>>(qbuf, kbuf, vbuf, cnt, bucket, pml, po);
  combine_kernel<<<4096, 256, 0, stream>>>(pml, po, AO2);
  // 7. proj GEMM (MFMA) + bias
  {
    dim3 grid(C_DIM / 64, N_TOK / 64);
    gemm_mfma<<<grid, 256, 0, stream>>>(AO2, WP2, nullptr, out, b_proj, C_DIM, 1);
  }
}

// Round 8
// 210.796 us; speedup vs baseline: 1.0722x; 1.0722x over previous
//
#include <hip/hip_runtime.h>
#include <hip/hip_bf16.h>
#include <math.h>

#define N_TOK 2048
#define C_DIM 512
#define H_NUM 8
#define DH 64
#define M_LM 64
#define SEG 32
#define KL 4
#define SCALE 0.125f

typedef __attribute__((ext_vector_type(8))) short short8;
typedef __attribute__((ext_vector_type(4))) short short4v;
typedef __attribute__((ext_vector_type(4))) float f32x4;

__device__ inline unsigned short f2bf(float f) {
  unsigned u = __float_as_uint(f);
  u += 0x7FFF + ((u >> 16) & 1);
  return (unsigned short)(u >> 16);
}
__device__ inline float bf2f(unsigned short h) {
  return __uint_as_float(((unsigned)h) << 16);
}

// ---------------------------------------------------------------------------
// Q/K fp32 GEMM — byte-identical to R5-R7 (bit-identical chain to R0;
// route path frozen). Do not touch.
// ---------------------------------------------------------------------------
__global__ __launch_bounds__(256) void gemm_qk(
    const float* __restrict__ A, const float* __restrict__ B,
    float* __restrict__ out_q, float* __restrict__ out_k)
{
  __shared__ float As[32][68];
  __shared__ float Bs[32][68];
  int tid = threadIdx.x;
  int tx = tid & 15, ty = tid >> 4;
  int row0 = blockIdx.y << 6;
  int col0 = blockIdx.x << 6;
  float acc[4][4] = {};
  int kk = tid & 31, rr = tid >> 5;

  float pa[8], pb[8];
#pragma unroll
  for (int i = 0; i < 8; i++) {
    pa[i] = A[(size_t)(row0 + rr + i * 8) * 512 + kk];
    pb[i] = B[(size_t)(col0 + rr + i * 8) * 512 + kk];
  }

  for (int k0 = 0; k0 < 512; k0 += 32) {
    __syncthreads();
#pragma unroll
    for (int i = 0; i < 8; i++) {
      As[kk][rr + i * 8] = pa[i];
      Bs[kk][rr + i * 8] = pb[i];
    }
    __syncthreads();
    if (k0 + 32 < 512) {
#pragma unroll
      for (int i = 0; i < 8; i++) {
        pa[i] = A[(size_t)(row0 + rr + i * 8) * 512 + k0 + 32 + kk];
        pb[i] = B[(size_t)(col0 + rr + i * 8) * 512 + k0 + 32 + kk];
      }
    }
#pragma unroll
    for (int kk2 = 0; kk2 < 32; kk2++) {
      float a[4], b[4];
      *(float4*)a = *(const float4*)&As[kk2][ty << 2];
      *(float4*)b = *(const float4*)&Bs[kk2][tx << 2];
#pragma unroll
      for (int i = 0; i < 4; i++)
#pragma unroll
        for (int j = 0; j < 4; j++) acc[i][j] += a[i] * b[j];
    }
  }

  int t = col0 >> 9;
  int h = (col0 >> 6) & 7;
  float* dst = (t == 0) ? out_q : out_k;
#pragma unroll
  for (int i = 0; i < 4; i++) {
    int n = row0 + (ty << 2) + i;
#pragma unroll
    for (int j = 0; j < 4; j++) {
      int d = (tx << 2) + j;
      dst[(size_t)((h << 11) + n) * DH + d] = acc[i][j];
    }
  }
}

// ---------------------------------------------------------------------------
// Fused 2-term bf16 splits (byte-identical to R5-R7).
// ---------------------------------------------------------------------------
__global__ void split3_kernel(const float* __restrict__ x, const float* __restrict__ wv,
                              const float* __restrict__ wp,
                              unsigned short* __restrict__ X2,
                              unsigned short* __restrict__ W2v,
                              unsigned short* __restrict__ WP2)
{
  int idx = blockIdx.x * 256 + threadIdx.x;
  const float* src; unsigned short* dst; int li;
  if (idx < 1048576)      { src = x;  dst = X2;  li = idx; }
  else if (idx < 1310720) { src = wv; dst = W2v; li = idx - 1048576; }
  else                    { src = wp; dst = WP2; li = idx - 1310720; }
  int r = li >> 9, k = li & 511;
  float a = src[li];
  unsigned short h1 = f2bf(a);
  float r1 = a - bf2f(h1);
  dst[(size_t)(r << 10) + k] = h1;
  dst[(size_t)(r << 10) + 512 + k] = f2bf(r1);
}

// ---------------------------------------------------------------------------
// bf16-split MFMA GEMM (byte-identical to R5-R7).
// ---------------------------------------------------------------------------
__global__ __launch_bounds__(256) void gemm_mfma(
    const unsigned short* __restrict__ A2, const unsigned short* __restrict__ B2,
    float* __restrict__ ov, float* __restrict__ ofull,
    const float* __restrict__ bias, int ldout, int mode)
{
  __shared__ short Al[4096];
  __shared__ short Bl[4096];
  int tid = threadIdx.x;
  int lane = tid & 63, w = tid >> 6;
  int row0 = blockIdx.y << 6, col0 = blockIdx.x << 6;
  int wr = (w >> 1) * 32, wc = (w & 1) * 32;
  int m_lo = tid & 7, h8 = (tid >> 3) & 7, m_hi = tid >> 6;
  int ms = m_hi * 8 + m_lo;
  int q = lane >> 4, ln = lane & 15;

  f32x4 acc[2][2];
#pragma unroll
  for (int mi = 0; mi < 2; mi++)
#pragma unroll
    for (int ni = 0; ni < 2; ni++)
#pragma unroll
      for (int r = 0; r < 4; r++) acc[mi][ni][r] = 0.0f;

  for (int s = 0; s < 24; s++) {
    int ka = (s < 8) ? s * 64 : (s < 16) ? 512 + (s - 8) * 64 : (s - 16) * 64;
    int kb = (s < 8) ? s * 64 : (s < 16) ? (s - 8) * 64 : 512 + (s - 16) * 64;
    short8 a0 = *(const short8*)(A2 + (size_t)(row0 + ms) * 1024 + ka + h8 * 8);
    short8 a1 = *(const short8*)(A2 + (size_t)(row0 + ms + 32) * 1024 + ka + h8 * 8);
    short8 b0 = *(const short8*)(B2 + (size_t)(col0 + ms) * 1024 + kb + h8 * 8);
    short8 b1 = *(const short8*)(B2 + (size_t)(col0 + ms + 32) * 1024 + kb + h8 * 8);
    __syncthreads();
    *(short8*)&Al[(h8 * 64 + ms) * 8] = a0;
    *(short8*)&Al[(h8 * 64 + ms + 32) * 8] = a1;
    *(short8*)&Bl[(h8 * 64 + ms) * 8] = b0;
    *(short8*)&Bl[(h8 * 64 + ms + 32) * 8] = b1;
    __syncthreads();
    short8 af[2][2], bf[2][2];
#pragma unroll
    for (int sub = 0; sub < 2; sub++)
#pragma unroll
      for (int i = 0; i < 2; i++) {
        af[sub][i] = *(const short8*)&Al[((sub * 4 + q) * 64 + wr + i * 16 + ln) * 8];
        bf[sub][i] = *(const short8*)&Bl[((sub * 4 + q) * 64 + wc + i * 16 + ln) * 8];
      }
#pragma unroll
    for (int sub = 0; sub < 2; sub++)
#pragma unroll
      for (int mi = 0; mi < 2; mi++)
#pragma unroll
        for (int ni = 0; ni < 2; ni++)
          acc[mi][ni] = __builtin_amdgcn_mfma_f32_16x16x32_bf16(
              af[sub][mi], bf[sub][ni], acc[mi][ni], 0, 0, 0);
  }

  if (mode == 0) {
    int hh = (col0 >> 6) & 7;
#pragma unroll
    for (int mi = 0; mi < 2; mi++)
#pragma unroll
      for (int ni = 0; ni < 2; ni++)
#pragma unroll
        for (int r = 0; r < 4; r++) {
          int row = row0 + wr + mi * 16 + q * 4 + r;
          int d = wc + ni * 16 + ln;
          ov[(size_t)((hh << 11) + row) * DH + d] = acc[mi][ni][r];
        }
  } else {
#pragma unroll
    for (int mi = 0; mi < 2; mi++)
#pragma unroll
      for (int ni = 0; ni < 2; ni++)
#pragma unroll
        for (int r = 0; r < 4; r++) {
          int row = row0 + wr + mi * 16 + q * 4 + r;
          int col = col0 + wc + ni * 16 + ln;
          ofull[(size_t)row * ldout + col] = acc[mi][ni][r] + bias[col];
        }
  }
}

// ---------------------------------------------------------------------------
// Centroids (byte-identical to R0).
// ---------------------------------------------------------------------------
__global__ void centroid_kernel(const float* __restrict__ kb, float* __restrict__ cent)
{
  int idx = blockIdx.x * blockDim.x + threadIdx.x;
  int m = (idx >> 6) & 63;
  int h = idx >> 12;
  int d = idx & 63;
  const float* base = kb + ((size_t)(h << 11) + m * SEG) * DH + d;
  float s = 0.f;
#pragma unroll
  for (int ss = 0; ss < SEG; ss++) s += base[(size_t)ss * DH];
  cent[idx] = s * (1.0f / SEG);
}

// ---------------------------------------------------------------------------
// Route + top-4 (byte-identical to R4-R7 passing version).
// ---------------------------------------------------------------------------
__global__ __launch_bounds__(256) void route_topk_kernel(
    const float* __restrict__ qb, const float* __restrict__ cent, int* __restrict__ topk)
{
  __shared__ float centT[64][65];
  __shared__ float qs[4][64];
  int tid = threadIdx.x;
  int wave = tid >> 6, lane = tid & 63;
  int qi = (blockIdx.x << 2) + wave;
  int h = qi >> 11;
  qs[wave][lane] = qb[(size_t)qi * DH + lane];
  const float4* c4 = (const float4*)(cent + ((size_t)h << 12));
#pragma unroll
  for (int i = 0; i < 4; i++) {
    int f4 = tid + 256 * i;
    int m = f4 >> 4;
    int d0 = (f4 & 15) * 4;
    float4 v = c4[f4];
    centT[d0][m] = v.x; centT[d0 + 1][m] = v.y;
    centT[d0 + 2][m] = v.z; centT[d0 + 3][m] = v.w;
  }
  __syncthreads();
  float dot = 0.f;
#pragma unroll
  for (int d = 0; d < 64; d++) dot += qs[wave][d] * centT[d][lane];
  float val = dot * SCALE;
  for (int r = 0; r < KL; r++) {
    float v = val;
    int id = lane;
#pragma unroll
    for (int off = 32; off; off >>= 1) {
      float ov = __shfl_xor(v, off, 64);
      int oi = __shfl_xor(id, off, 64);
      if (ov > v || (ov == v && oi < id)) { v = ov; id = oi; }
    }
    if (lane == 0) topk[qi * KL + r] = id;
    if (lane == id) val = -INFINITY;
  }
}

// ---------------------------------------------------------------------------
// Bin: bucket (query, slot) pairs by (h, seg). Entry = n | (r<<11).
// ---------------------------------------------------------------------------
__global__ void bin_kernel(const int* __restrict__ topk, int* __restrict__ cnt,
                           unsigned short* __restrict__ bucket)
{
  int qi = blockIdx.x * 256 + threadIdx.x;
  int4 tk = *(const int4*)(topk + qi * KL);
  int segs[4] = {tk.x, tk.y, tk.z, tk.w};
  int h = qi >> 11, n = qi & 2047;
#pragma unroll
  for (int r = 0; r < KL; r++) {
    int hs = (h << 6) | segs[r];
    int pos = atomicAdd(&cnt[hs], 1);
    bucket[hs * 2048 + pos] = (unsigned short)(n | (r << 11));
  }
}

// ---------------------------------------------------------------------------
// Scan: chunkPrefix over ceil(cnt/32) for the 512 buckets (1 block, 512 thr).
// ---------------------------------------------------------------------------
__global__ void scan_kernel(const int* __restrict__ cnt, int* __restrict__ pref)
{
  __shared__ int s[512];
  int t = threadIdx.x;
  s[t] = (cnt[t] + 31) >> 5;
  __syncthreads();
  for (int off = 1; off < 512; off <<= 1) {
    int x = (t >= off) ? s[t - off] : 0;
    __syncthreads();
    s[t] += x;
    __syncthreads();
  }
  pref[t + 1] = s[t];
  if (t == 0) pref[0] = 0;
}

// ---------------------------------------------------------------------------
// Attend via MFMA: one block per 32-query chunk of one (h,seg) bucket.
// S = Q·K^T (32x32, K=64, 3 bf16-split products) -> softmax partials ->
// O = P·V (32x64, K=32, 3 products). LDS layout chunk-major
// [(k>>3)*rows + m]*8 + (k&7) as in gemm_mfma. V staged transposed.
// ---------------------------------------------------------------------------
__global__ __launch_bounds__(256) void attend_mfma(
    const float* __restrict__ qb, const float* __restrict__ kb,
    const float* __restrict__ vb, const int* __restrict__ cnt,
    const unsigned short* __restrict__ bucket, const int* __restrict__ pref,
    float2* __restrict__ pml, float* __restrict__ po)
{
  __shared__ short Qs[16 * 32 * 8];   // 8 KB: 32 q-rows x 128 k (hi|lo)
  __shared__ short Ks[16 * 32 * 8];   // 8 KB: 32 key-rows x 128 k
  __shared__ short Vt[8 * 64 * 8];    // 8 KB: 64 d-rows x 64 k (key hi|lo)
  __shared__ float Sl[32][36];
  __shared__ short P2[8 * 32 * 8];    // 4 KB: 32 q-rows x 64 k (key hi|lo)
  __shared__ int entL[32];
  int b = blockIdx.x;
  if (b >= pref[512]) return;
  int lo = 0, hi = 512;
  while (hi - lo > 1) { int mid = (lo + hi) >> 1; if (pref[mid] <= b) lo = mid; else hi = mid; }
  int hs = lo;
  int j = b - pref[hs];
  int h = hs >> 6, seg = hs & 63;
  int c = cnt[hs];
  int tid = threadIdx.x;

  // phase A: entries + K + V^T staging
  if (tid < 32) {
    int i = j * 32 + tid;
    entL[tid] = (i < c) ? (int)bucket[hs * 2048 + i] : 0xFFFF;
  }
  {
    int row = tid & 31, part = tid >> 5;
    float x[8];
    const float* kr = kb + ((size_t)(h << 11) + seg * SEG + row) * DH + part * 8;
    *(float4*)&x[0] = *(const float4*)kr;
    *(float4*)&x[4] = *(const float4*)(kr + 4);
    short h8[8], l8[8];
#pragma unroll
    for (int q = 0; q < 8; q++) {
      unsigned short hb = f2bf(x[q]);
      h8[q] = hb; l8[q] = f2bf(x[q] - bf2f(hb));
    }
    *(short8*)&Ks[(part * 32 + row) * 8] = *(short8*)h8;
    *(short8*)&Ks[((8 + part) * 32 + row) * 8] = *(short8*)l8;
    const float* vr = vb + ((size_t)(h << 11) + seg * SEG + row) * DH + part * 8;
    *(float4*)&x[0] = *(const float4*)vr;
    *(float4*)&x[4] = *(const float4*)(vr + 4);
    int cdh = row >> 3, kj = row & 7;
#pragma unroll
    for (int q = 0; q < 8; q++) {
      int d = part * 8 + q;
      unsigned short hb = f2bf(x[q]);
      Vt[(cdh * 64 + d) * 8 + kj] = hb;
      Vt[((4 + cdh) * 64 + d) * 8 + kj] = f2bf(x[q] - bf2f(hb));
    }
  }
  __syncthreads();
  // phase B: Q staging (gathered via entries)
  {
    int row = tid & 31, part = tid >> 5;
    int n = entL[row] & 2047;      // sentinel -> row 0, masked at write
    float x[8];
    const float* qr = qb + ((size_t)(h << 11) + n) * DH + part * 8;
    *(float4*)&x[0] = *(const float4*)qr;
    *(float4*)&x[4] = *(const float4*)(qr + 4);
    short h8[8], l8[8];
#pragma unroll
    for (int q = 0; q < 8; q++) {
      unsigned short hb = f2bf(x[q]);
      h8[q] = hb; l8[q] = f2bf(x[q] - bf2f(hb));
    }
    *(short8*)&Qs[(part * 32 + row) * 8] = *(short8*)h8;
    *(short8*)&Qs[((8 + part) * 32 + row) * 8] = *(short8*)l8;
  }
  __syncthreads();
  // QK^T: wave w computes 16x16 tile (m0,n0)
  int w = tid >> 6, lane = tid & 63, ln = lane & 15, quad = lane >> 4;
  int m0 = (w & 1) * 16, n0 = (w >> 1) * 16;
  {
    f32x4 acc = {0.f, 0.f, 0.f, 0.f};
#pragma unroll
    for (int sidx = 0; sidx < 3; sidx++) {
      int qa = (sidx == 1) ? 8 : 0;     // (0,0),(1,0),(0,1)
      int ka = (sidx == 2) ? 8 : 0;
#pragma unroll
      for (int kh = 0; kh < 2; kh++) {
        short8 a  = *(const short8*)&Qs[((qa + kh * 4 + quad) * 32 + m0 + ln) * 8];
        short8 bb = *(const short8*)&Ks[((ka + kh * 4 + quad) * 32 + n0 + ln) * 8];
        acc = __builtin_amdgcn_mfma_f32_16x16x32_bf16(a, bb, acc, 0, 0, 0);
      }
    }
#pragma unroll
    for (int r = 0; r < 4; r++)
      Sl[m0 + quad * 4 + r][n0 + ln] = acc[r] * SCALE;
  }
  __syncthreads();
  // softmax partials: thread (row = tid>>3, c8 = tid&7) handles 4 keys
  {
    int row = tid >> 3, c8 = tid & 7;
    float4 s4 = *(const float4*)&Sl[row][c8 * 4];
    float mx = fmaxf(fmaxf(s4.x, s4.y), fmaxf(s4.z, s4.w));
#pragma unroll
    for (int off = 1; off < 8; off <<= 1) mx = fmaxf(mx, __shfl_xor(mx, off, 64));
    float ev[4];
    ev[0] = expf(s4.x - mx); ev[1] = expf(s4.y - mx);
    ev[2] = expf(s4.z - mx); ev[3] = expf(s4.w - mx);
    float ls = ev[0] + ev[1] + ev[2] + ev[3];
#pragma unroll
    for (int off = 1; off < 8; off <<= 1) ls += __shfl_xor(ls, off, 64);
    short hh[4], llo[4];
#pragma unroll
    for (int q = 0; q < 4; q++) {
      unsigned short hb = f2bf(ev[q]);
      hh[q] = hb; llo[q] = f2bf(ev[q] - bf2f(hb));
    }
    int cd = c8 >> 1, koff = (c8 & 1) * 4;
    *(short4v*)&P2[(cd * 32 + row) * 8 + koff] = *(short4v*)hh;
    *(short4v*)&P2[((4 + cd) * 32 + row) * 8 + koff] = *(short4v*)llo;
    if (c8 == 0) {
      int e = entL[row];
      if (!(e & 0x8000)) {
        int qn = e & 2047, rr = (e >> 11) & 3;
        int p = (((h << 11) | qn) << 2) | rr;
        pml[p] = make_float2(mx, ls);
      }
    }
  }
  __syncthreads();
  // PV: wave w computes rows m0, cols n0c..n0c+31 (two 16x16 tiles)
  {
    int n0c = (w >> 1) * 32;
    f32x4 accO[2];
#pragma unroll
    for (int t16 = 0; t16 < 2; t16++)
#pragma unroll
      for (int r = 0; r < 4; r++) accO[t16][r] = 0.f;
#pragma unroll
    for (int t16 = 0; t16 < 2; t16++) {
#pragma unroll
      for (int sidx = 0; sidx < 3; sidx++) {
        int pa = (sidx == 1) ? 4 : 0;
        int va = (sidx == 2) ? 4 : 0;
        short8 a  = *(const short8*)&P2[((pa + quad) * 32 + m0 + ln) * 8];
        short8 bb = *(const short8*)&Vt[((va + quad) * 64 + n0c + t16 * 16 + ln) * 8];
        accO[t16] = __builtin_amdgcn_mfma_f32_16x16x32_bf16(a, bb, accO[t16], 0, 0, 0);
      }
    }
#pragma unroll
    for (int t16 = 0; t16 < 2; t16++)
#pragma unroll
      for (int r = 0; r < 4; r++) {
        int row = m0 + quad * 4 + r;
        int e = entL[row];
        if (e & 0x8000) continue;
        int qn = e & 2047, rr = (e >> 11) & 3;
        int p = (((h << 11) | qn) << 2) | rr;
        po[(size_t)p * 64 + n0c + t16 * 16 + ln] = accO[t16][r];
      }
  }
}

// ---------------------------------------------------------------------------
// Combine the 4 per-segment partials per query; emit bf16 hi|lo split.
// ---------------------------------------------------------------------------
__global__ void combine_kernel(const float2* __restrict__ pml,
                               const float* __restrict__ po,
                               unsigned short* __restrict__ ao2)
{
  int idx = blockIdx.x * 256 + threadIdx.x;
  int d = idx & 63;
  int qi = idx >> 6;
  int h = qi >> 11, n = qi & 2047;
  float2 ml0 = pml[qi * 4 + 0], ml1 = pml[qi * 4 + 1];
  float2 ml2 = pml[qi * 4 + 2], ml3 = pml[qi * 4 + 3];
  float M = fmaxf(fmaxf(ml0.x, ml1.x), fmaxf(ml2.x, ml3.x));
  float w0 = expf(ml0.x - M), w1 = expf(ml1.x - M);
  float w2 = expf(ml2.x - M), w3 = expf(ml3.x - M);
  float L = w0 * ml0.y + w1 * ml1.y + w2 * ml2.y + w3 * ml3.y;
  float o = w0 * po[(size_t)(qi * 4 + 0) * 64 + d]
          + w1 * po[(size_t)(qi * 4 + 1) * 64 + d]
          + w2 * po[(size_t)(qi * 4 + 2) * 64 + d]
          + w3 * po[(size_t)(qi * 4 + 3) * 64 + d];
  o /= L;
  unsigned short hb = f2bf(o);
  unsigned short lb = f2bf(o - bf2f(hb));
  size_t off0 = (size_t)n * 1024 + (h << 6) + d;
  ao2[off0] = hb;
  ao2[off0 + 512] = lb;
}

// ---------------------------------------------------------------------------
extern "C" void kernel_launch(void* const* d_in, const int* in_sizes, int n_in,
                              void* d_out, int out_size, void* d_ws, size_t ws_size,
                              hipStream_t stream)
{
  const float* x      = (const float*)d_in[0];
  const float* w_qkv  = (const float*)d_in[1];
  const float* w_proj = (const float*)d_in[2];
  const float* b_proj = (const float*)d_in[3];
  float* out = (float*)d_out;

  float* base = (float*)d_ws;
  float* qbuf = base;                                   // 1,048,576 f
  float* kbuf = base + 1048576;
  float* vbuf = base + 2097152;
  float* cent = base + 3145728;                         // 32,768 f
  int*   topk = (int*)(base + 3178496);                 // 65,536 i
  unsigned short* X2  = (unsigned short*)(base + 3244032);  // 2048x1024 bf16
  unsigned short* W2v = (unsigned short*)(base + 4292608);  // 512x1024
  unsigned short* WP2 = (unsigned short*)(base + 4554752);  // 512x1024
  unsigned short* AO2 = X2;  // overlay: X2 dead after V GEMM
  int* cnt = (int*)(base + 4816896);                        // 512 ints
  unsigned short* bucket = (unsigned short*)(base + 4817408);  // 512*2048 u16
  float2* pml = (float2*)(base + 5341696);                  // 65,536 float2
  float* po   = base + 5472768;                             // 65,536*64 f
  int* pref   = (int*)(base + 9667072);                     // 513 ints

  // 1. fused 2-term bf16 splits
  split3_kernel<<<6144, 256, 0, stream>>>(x, w_qkv + 1024 * 512, w_proj,
                                          X2, W2v, WP2);
  // 2. Q/K fp32 (bit-identical chain to R0; route path frozen)
  {
    dim3 grid(1024 / 64, N_TOK / 64);
    gemm_qk<<<grid, 256, 0, stream>>>(x, w_qkv, qbuf, kbuf);
  }
  // 3. V via bf16-split MFMA
  {
    dim3 grid(512 / 64, N_TOK / 64);
    gemm_mfma<<<grid, 256, 0, stream>>>(X2, W2v, vbuf, nullptr, nullptr, 0, 0);
  }
  // 4. centroids
  centroid_kernel<<<(H_NUM * M_LM * DH) / 256, 256, 0, stream>>>(kbuf, cent);
  // 5. route + top-4 (bit-exact vs R0)
  route_topk_kernel<<<(H_NUM * N_TOK) / 4, 256, 0, stream>>>(qbuf, cent, topk);
  // 6. segment-major MFMA attention
  hipMemsetAsync(cnt, 0, 512 * sizeof(int), stream);
  bin_kernel<<<64, 256, 0, stream>>>(topk, cnt, bucket);
  scan_kernel<<<1, 512, 0, stream>>>(cnt, pref);
  attend_mfma<<<2560, 256, 0, stream>>>(qbuf, kbuf, vbuf, cnt, bucket, pref, pml, po);
  combine_kernel<<<4096, 256, 0, stream>>>(pml, po, AO2);
  // 7. proj GEMM (MFMA) + bias
  {
    dim3 grid(C_DIM / 64, N_TOK / 64);
    gemm_mfma<<<grid, 256, 0, stream>>>(AO2, WP2, nullptr, out, b_proj, C_DIM, 1);
  }
}